// Round 4
// baseline (426.689 us; speedup 1.0000x reference)
//
#include <hip/hip_runtime.h>

#define B_ 8
#define L_ 2048
#define D_ 512
#define BI 64
#define BJ 32
#define JSPLIT 2
#define JHALF (L_ / JSPLIT)        // 1024
#define JITERS (JHALF / BJ)        // 32
#define KTILE (BJ * D_)            // 16384 f16 = 32 KB
#define PSTRIDE 40
#define NROWS (B_ * L_)            // 16384

typedef __attribute__((ext_vector_type(4))) float  floatx4;
typedef __attribute__((ext_vector_type(8))) _Float16 halfx8;
typedef __attribute__((ext_vector_type(4))) int    intx4;

static __device__ __forceinline__ unsigned int f2h_bits(float x) {
  _Float16 h = (_Float16)x;
  return (unsigned int)__builtin_bit_cast(unsigned short, h);
}

static __device__ __forceinline__ void async_ld16(const unsigned short* g,
                                                  unsigned short* l) {
  __builtin_amdgcn_global_load_lds(
      (const __attribute__((address_space(1))) unsigned int*)g,
      (__attribute__((address_space(3))) unsigned int*)l, 16, 0, 0);
}

// 16-lane butterfly reductions on the VALU (DPP), replacing LDS-pipe shuffles.
static __device__ __forceinline__ float dpp_bfly_max(float x) {
  int v; float y;
  v = __builtin_bit_cast(int, x);
  y = __builtin_bit_cast(float, __builtin_amdgcn_update_dpp(v, v, 0xB1, 0xF, 0xF, true));
  x = fmaxf(x, y);
  v = __builtin_bit_cast(int, x);
  y = __builtin_bit_cast(float, __builtin_amdgcn_update_dpp(v, v, 0x4E, 0xF, 0xF, true));
  x = fmaxf(x, y);
  v = __builtin_bit_cast(int, x);
  y = __builtin_bit_cast(float, __builtin_amdgcn_update_dpp(v, v, 0x141, 0xF, 0xF, true));
  x = fmaxf(x, y);
  v = __builtin_bit_cast(int, x);
  y = __builtin_bit_cast(float, __builtin_amdgcn_update_dpp(v, v, 0x140, 0xF, 0xF, true));
  x = fmaxf(x, y);
  return x;
}

static __device__ __forceinline__ float dpp_bfly_sum(float x) {
  int v; float y;
  v = __builtin_bit_cast(int, x);
  y = __builtin_bit_cast(float, __builtin_amdgcn_update_dpp(v, v, 0xB1, 0xF, 0xF, true));
  x += y;
  v = __builtin_bit_cast(int, x);
  y = __builtin_bit_cast(float, __builtin_amdgcn_update_dpp(v, v, 0x4E, 0xF, 0xF, true));
  x += y;
  v = __builtin_bit_cast(int, x);
  y = __builtin_bit_cast(float, __builtin_amdgcn_update_dpp(v, v, 0x141, 0xF, 0xF, true));
  x += y;
  v = __builtin_bit_cast(int, x);
  y = __builtin_bit_cast(float, __builtin_amdgcn_update_dpp(v, v, 0x140, 0xF, 0xF, true));
  x += y;
  return x;
}

// ---------------------------------------------------------------------------
// prep: Kh[b][j][d-granules swizzled by j&7] = in*kw   (for LDS-staged K frags)
//       Vt[b][d][L] = in*vw, LINEAR transposed (read direct from L2 by flash)
// grid (L/64, D/64, B/2), 256 threads; kw/vw regs reused across 2 batches.
// ---------------------------------------------------------------------------
__global__ __launch_bounds__(256) void prep(const float* __restrict__ in,
                                            const float* __restrict__ kw,
                                            const float* __restrict__ vw,
                                            unsigned short* __restrict__ Kh,
                                            unsigned short* __restrict__ Vt) {
  const int lt = blockIdx.x * 64;
  const int dt = blockIdx.y * 64;
  const int t  = threadIdx.x;
  __shared__ unsigned short vtile[64][66];

  float4 kwv[4], vwv[4];
  #pragma unroll
  for (int i = 0; i < 4; ++i) {
    int c = i * 256 + t, r = c >> 4, c4 = (c & 15) * 4;
    size_t wi = (size_t)(lt + r) * D_ + dt + c4;
    kwv[i] = *(const float4*)(kw + wi);
    vwv[i] = *(const float4*)(vw + wi);
  }

  for (int bb = 0; bb < 2; ++bb) {
    const int b = blockIdx.z * 2 + bb;
    #pragma unroll
    for (int i = 0; i < 4; ++i) {
      int c = i * 256 + t, r = c >> 4, c4 = (c & 15) * 4;
      int j = lt + r;
      size_t gi = ((size_t)b * L_ + j) * D_ + dt + c4;
      float4 iv = *(const float4*)(in + gi);
      unsigned int p0 = f2h_bits(iv.x * kwv[i].x) | (f2h_bits(iv.y * kwv[i].y) << 16);
      unsigned int p1 = f2h_bits(iv.z * kwv[i].z) | (f2h_bits(iv.w * kwv[i].w) << 16);
      int gs = (((dt + c4) >> 3) ^ (j & 7));
      uint2 pk; pk.x = p0; pk.y = p1;
      *(uint2*)(Kh + ((size_t)b * L_ + j) * D_ + gs * 8 + (c4 & 7)) = pk;
      vtile[r][c4 + 0] = (unsigned short)f2h_bits(iv.x * vwv[i].x);
      vtile[r][c4 + 1] = (unsigned short)f2h_bits(iv.y * vwv[i].y);
      vtile[r][c4 + 2] = (unsigned short)f2h_bits(iv.z * vwv[i].z);
      vtile[r][c4 + 3] = (unsigned short)f2h_bits(iv.w * vwv[i].w);
    }
    __syncthreads();
    #pragma unroll
    for (int i = 0; i < 2; ++i) {
      int c = i * 256 + t, dd = c >> 3, l8 = (c & 7) * 8;
      int ov[4];
      #pragma unroll
      for (int k2 = 0; k2 < 4; ++k2)
        ov[k2] = (int)((unsigned int)vtile[l8 + 2 * k2][dd] |
                       ((unsigned int)vtile[l8 + 2 * k2 + 1][dd] << 16));
      intx4 o; o[0] = ov[0]; o[1] = ov[1]; o[2] = ov[2]; o[3] = ov[3];
      *(intx4*)(Vt + ((size_t)b * D_ + (dt + dd)) * L_ + (lt + l8)) = o;
    }
    __syncthreads();
  }
}

// ---------------------------------------------------------------------------
// flash: grid (L/BI, JSPLIT*B), 256 thr = 4 waves, wave owns a 16-row i-strip.
// K double-buffered via global_load_lds (1 barrier/iter, prefetch covered);
// V fragments read DIRECTLY from global (L2) — no LDS staging for V.
// ---------------------------------------------------------------------------
static __device__ __forceinline__ void stage_K(const unsigned short* Kg,
                                               unsigned short* Kl, int tid) {
  const int wb = tid & 192;  // wave base (uniform per wave)
  #pragma unroll
  for (int i = 0; i < 8; ++i) {
    int gl = i * 256 + tid;
    async_ld16(Kg + (size_t)gl * 8, Kl + (i * 256 + wb) * 8);
  }
}

__global__ __launch_bounds__(256, 2) void flash(const float* __restrict__ in,
                                                const float* __restrict__ qw,
                                                const unsigned short* __restrict__ Kh,
                                                const unsigned short* __restrict__ Vt,
                                                _Float16* __restrict__ Oh,
                                                float2* __restrict__ ml) {
  const int b    = blockIdx.y >> 1;
  const int g    = blockIdx.y & 1;       // j-half
  const int i0   = blockIdx.x * BI;
  const int tid  = threadIdx.x;
  const int w    = tid >> 6;
  const int lane = tid & 63;
  const int ln16 = lane & 15;
  const int quad = lane >> 4;

  __shared__ unsigned short Ksh[2 * KTILE];      // 64 KB (double buffer)
  __shared__ unsigned short Psh[BI * PSTRIDE];   //  5 KB

  const float kScale = 0.51012599f;  // log2(e)/sqrt(8): exp2-domain softmax

  // ---- Q fragments in registers (A-layout: m=ln16, k=quad*8+t) ----
  halfx8 qf[16];
  {
    const int qi = i0 + w * 16 + ln16;
    const float* ip = in + ((size_t)b * L_ + qi) * D_;
    const float* wp = qw + (size_t)qi * D_;
    #pragma unroll
    for (int ks = 0; ks < 16; ++ks) {
      int d0 = ks * 32 + quad * 8;
      float4 a0 = *(const float4*)(ip + d0);
      float4 a1 = *(const float4*)(ip + d0 + 4);
      float4 w0 = *(const float4*)(wp + d0);
      float4 w1 = *(const float4*)(wp + d0 + 4);
      halfx8 q;
      q[0] = (_Float16)(a0.x * w0.x * kScale);
      q[1] = (_Float16)(a0.y * w0.y * kScale);
      q[2] = (_Float16)(a0.z * w0.z * kScale);
      q[3] = (_Float16)(a0.w * w0.w * kScale);
      q[4] = (_Float16)(a1.x * w1.x * kScale);
      q[5] = (_Float16)(a1.y * w1.y * kScale);
      q[6] = (_Float16)(a1.z * w1.z * kScale);
      q[7] = (_Float16)(a1.w * w1.w * kScale);
      qf[ks] = q;
    }
  }

  float m_r[4], l_r[4];
  #pragma unroll
  for (int r = 0; r < 4; ++r) { m_r[r] = -1e30f; l_r[r] = 0.f; }
  floatx4 O[32];
  #pragma unroll
  for (int ct = 0; ct < 32; ++ct) O[ct] = (floatx4){0.f, 0.f, 0.f, 0.f};

  const unsigned short* KgB = Kh + ((size_t)b * L_ + g * JHALF) * D_;
  // V frag base: lane ln16 -> d-row (ct*16+ln16), quad -> j-chunk
  const unsigned short* vbase0 =
      Vt + (size_t)b * D_ * L_ + (size_t)ln16 * L_ + g * JHALF + quad * 8;
  const int xk = ln16 & 7;

  stage_K(KgB, Ksh, tid);  // prologue: tile 0 -> buf 0

  for (int jb = 0; jb < JITERS; ++jb) {
    const int s = jb & 1;
    __syncthreads();  // drains vmcnt(0): K(jb) staged in buf[s]
    if (jb + 1 < JITERS)
      stage_K(KgB + (size_t)(jb + 1) * KTILE, Ksh + (s ^ 1) * KTILE, tid);

    const unsigned short* vbase = vbase0 + jb * BJ;

    // ---- V chunk 0 prefetch (latency hides under QK's LDS+MFMA phase) ----
    halfx8 va[4], vb[4];
    #pragma unroll
    for (int t2 = 0; t2 < 4; ++t2)
      va[t2] = *(const halfx8*)(vbase + (size_t)t2 * 16 * L_);

    // ---- S = Q K^T ----
    const unsigned short* Kc = Ksh + s * KTILE;
    floatx4 acc[2][2];
    #pragma unroll
    for (int jt = 0; jt < 2; ++jt) {
      acc[jt][0] = (floatx4){0.f, 0.f, 0.f, 0.f};
      acc[jt][1] = (floatx4){0.f, 0.f, 0.f, 0.f};
      const unsigned short* kr = Kc + (size_t)(jt * 16 + ln16) * D_;
      #pragma unroll
      for (int ks = 0; ks < 16; ++ks) {
        halfx8 bk = *(const halfx8*)(kr + (((4 * ks + quad) ^ xk) * 8));
        acc[jt][ks & 1] =
            __builtin_amdgcn_mfma_f32_16x16x32_f16(qf[ks], bk, acc[jt][ks & 1], 0, 0, 0);
      }
    }
    floatx4 sA[2];
    sA[0] = acc[0][0] + acc[0][1];
    sA[1] = acc[1][0] + acc[1][1];

    // ---- online softmax (DPP butterfly, VALU pipe) ----
    float mt[4];
    #pragma unroll
    for (int r = 0; r < 4; ++r) mt[r] = dpp_bfly_max(fmaxf(sA[0][r], sA[1][r]));
    float al[4], ts[4];
    bool upd = false;
    #pragma unroll
    for (int r = 0; r < 4; ++r) {
      float mn = fmaxf(m_r[r], mt[r]);
      al[r] = exp2f(m_r[r] - mn);
      upd = upd || (mn != m_r[r]);
      m_r[r] = mn;
      float e0 = exp2f(sA[0][r] - mn);
      float e1 = exp2f(sA[1][r] - mn);
      sA[0][r] = e0; sA[1][r] = e1;
      ts[r] = dpp_bfly_sum(e0 + e1);
    }
    #pragma unroll
    for (int r = 0; r < 4; ++r) l_r[r] = l_r[r] * al[r] + ts[r];

    if (__any((int)upd)) {
      #pragma unroll
      for (int ct = 0; ct < 32; ++ct) {
        #pragma unroll
        for (int r = 0; r < 4; ++r) O[ct][r] *= al[r];
      }
    }

    // ---- P: C-layout regs -> A-layout via LDS (same wave, no barrier) ----
    #pragma unroll
    for (int jt = 0; jt < 2; ++jt) {
      #pragma unroll
      for (int r = 0; r < 4; ++r)
        Psh[(w * 16 + quad * 4 + r) * PSTRIDE + jt * 16 + ln16] =
            (unsigned short)f2h_bits(sA[jt][r]);
    }
    halfx8 pf = *(const halfx8*)(&Psh[(w * 16 + ln16) * PSTRIDE + quad * 8]);

    // ---- O += P V : V frags direct from L2, 2-deep chunk pipeline ----
    #pragma unroll
    for (int c = 0; c < 8; ++c) {
      halfx8* cur = (c & 1) ? vb : va;
      halfx8* nxt = (c & 1) ? va : vb;
      if (c < 7) {
        #pragma unroll
        for (int t2 = 0; t2 < 4; ++t2)
          nxt[t2] = *(const halfx8*)(vbase + (size_t)(4 * (c + 1) + t2) * 16 * L_);
      }
      #pragma unroll
      for (int t2 = 0; t2 < 4; ++t2)
        O[4 * c + t2] =
            __builtin_amdgcn_mfma_f32_16x16x32_f16(pf, cur[t2], O[4 * c + t2], 0, 0, 0);
    }
  }

  // ---- partial epilogue: Oh = O/l (f16), ml = (m, l) ----
  float inv[4];
  #pragma unroll
  for (int r = 0; r < 4; ++r) inv[r] = 1.0f / l_r[r];
  const size_t rowbase = (size_t)g * NROWS + (size_t)b * L_ + i0 + w * 16;
  _Float16* op = Oh + rowbase * D_;
  #pragma unroll
  for (int r = 0; r < 4; ++r) {
    int row = quad * 4 + r;
    #pragma unroll
    for (int ct = 0; ct < 32; ++ct)
      op[(size_t)row * D_ + ct * 16 + ln16] = (_Float16)(O[ct][r] * inv[r]);
  }
  if (ln16 == 0) {
    #pragma unroll
    for (int r = 0; r < 4; ++r) {
      float2 v; v.x = m_r[r]; v.y = l_r[r];
      ml[rowbase + quad * 4 + r] = v;
    }
  }
}

// ---------------------------------------------------------------------------
// combine: out = (a1*O1 + a2*O2)/(a1+a2), a_g = exp2(m_g - M) * l_g
// ---------------------------------------------------------------------------
__global__ __launch_bounds__(256) void combine(const _Float16* __restrict__ Oh,
                                               const float2* __restrict__ ml,
                                               float* __restrict__ out) {
  const int row = blockIdx.x * 4 + (threadIdx.x >> 6);
  const int d0  = (threadIdx.x & 63) * 8;
  float2 m1 = ml[row];
  float2 m2 = ml[NROWS + row];
  float M  = fmaxf(m1.x, m2.x);
  float a1 = exp2f(m1.x - M) * m1.y;
  float a2 = exp2f(m2.x - M) * m2.y;
  float inv = 1.0f / (a1 + a2);
  float w1 = a1 * inv, w2 = a2 * inv;
  halfx8 o1 = *(const halfx8*)(Oh + (size_t)row * D_ + d0);
  halfx8 o2 = *(const halfx8*)(Oh + ((size_t)NROWS + row) * D_ + d0);
  float4 r0, r1;
  r0.x = w1 * (float)o1[0] + w2 * (float)o2[0];
  r0.y = w1 * (float)o1[1] + w2 * (float)o2[1];
  r0.z = w1 * (float)o1[2] + w2 * (float)o2[2];
  r0.w = w1 * (float)o1[3] + w2 * (float)o2[3];
  r1.x = w1 * (float)o1[4] + w2 * (float)o2[4];
  r1.y = w1 * (float)o1[5] + w2 * (float)o2[5];
  r1.z = w1 * (float)o1[6] + w2 * (float)o2[6];
  r1.w = w1 * (float)o1[7] + w2 * (float)o2[7];
  *(float4*)(out + (size_t)row * D_ + d0)     = r0;
  *(float4*)(out + (size_t)row * D_ + d0 + 4) = r1;
}

// ---------------------------------------------------------------------------
extern "C" void kernel_launch(void* const* d_in, const int* in_sizes, int n_in,
                              void* d_out, int out_size, void* d_ws, size_t ws_size,
                              hipStream_t stream) {
  const float* in = (const float*)d_in[0];
  const float* qw = (const float*)d_in[1];
  const float* kw = (const float*)d_in[2];
  const float* vw = (const float*)d_in[3];
  float* out = (float*)d_out;

  unsigned short* Kh = (unsigned short*)d_ws;                 // 16.78 MB
  unsigned short* Vt = Kh + (size_t)B_ * L_ * D_;             // 16.78 MB
  _Float16* Oh = (_Float16*)(Vt + (size_t)B_ * L_ * D_);      // 33.55 MB
  float2* ml = (float2*)(Oh + (size_t)JSPLIT * NROWS * D_);   //  0.26 MB

  prep<<<dim3(L_ / 64, D_ / 64, B_ / 2), dim3(256), 0, stream>>>(in, kw, vw, Kh, Vt);
  flash<<<dim3(L_ / BI, JSPLIT * B_), dim3(256), 0, stream>>>(in, qw, Kh, Vt, Oh, ml);
  combine<<<dim3(NROWS / 4), dim3(256), 0, stream>>>(Oh, ml, out);
}

// Round 5
// 380.888 us; speedup vs baseline: 1.1202x; 1.1202x over previous
//
#include <hip/hip_runtime.h>

#define B_ 8
#define L_ 2048
#define D_ 512
#define BI 64
#define BJ 32
#define JSPLIT 2
#define JHALF (L_ / JSPLIT)        // 1024
#define JITERS (JHALF / BJ)        // 32
#define KTILE (BJ * D_)            // 16384 f16 = 32 KB
#define VTILE (D_ * BJ)            // 16384 f16 = 32 KB
#define PSTRIDE 40
#define NROWS (B_ * L_)            // 16384

typedef __attribute__((ext_vector_type(4))) float  floatx4;
typedef __attribute__((ext_vector_type(8))) _Float16 halfx8;
typedef __attribute__((ext_vector_type(4))) int    intx4;

static __device__ __forceinline__ unsigned int f2h_bits(float x) {
  _Float16 h = (_Float16)x;
  return (unsigned int)__builtin_bit_cast(unsigned short, h);
}

static __device__ __forceinline__ void async_ld16(const unsigned short* g,
                                                  unsigned short* l) {
  __builtin_amdgcn_global_load_lds(
      (const __attribute__((address_space(1))) unsigned int*)g,
      (__attribute__((address_space(3))) unsigned int*)l, 16, 0, 0);
}

// 16-lane butterfly reductions on the VALU (DPP) — off the LDS pipe.
static __device__ __forceinline__ float dpp_bfly_max(float x) {
  int v; float y;
  v = __builtin_bit_cast(int, x);
  y = __builtin_bit_cast(float, __builtin_amdgcn_update_dpp(v, v, 0xB1, 0xF, 0xF, true));
  x = fmaxf(x, y);
  v = __builtin_bit_cast(int, x);
  y = __builtin_bit_cast(float, __builtin_amdgcn_update_dpp(v, v, 0x4E, 0xF, 0xF, true));
  x = fmaxf(x, y);
  v = __builtin_bit_cast(int, x);
  y = __builtin_bit_cast(float, __builtin_amdgcn_update_dpp(v, v, 0x141, 0xF, 0xF, true));
  x = fmaxf(x, y);
  v = __builtin_bit_cast(int, x);
  y = __builtin_bit_cast(float, __builtin_amdgcn_update_dpp(v, v, 0x140, 0xF, 0xF, true));
  x = fmaxf(x, y);
  return x;
}

static __device__ __forceinline__ float dpp_bfly_sum(float x) {
  int v; float y;
  v = __builtin_bit_cast(int, x);
  y = __builtin_bit_cast(float, __builtin_amdgcn_update_dpp(v, v, 0xB1, 0xF, 0xF, true));
  x += y;
  v = __builtin_bit_cast(int, x);
  y = __builtin_bit_cast(float, __builtin_amdgcn_update_dpp(v, v, 0x4E, 0xF, 0xF, true));
  x += y;
  v = __builtin_bit_cast(int, x);
  y = __builtin_bit_cast(float, __builtin_amdgcn_update_dpp(v, v, 0x141, 0xF, 0xF, true));
  x += y;
  v = __builtin_bit_cast(int, x);
  y = __builtin_bit_cast(float, __builtin_amdgcn_update_dpp(v, v, 0x140, 0xF, 0xF, true));
  x += y;
  return x;
}

// ---------------------------------------------------------------------------
// prep: Kh[b][j][d-granules swizzled by j&7] = in*kw
//       Vt[b][d][jtile][j-granules swizzled by (d^(d>>2))&3] = in*vw
// grid (L/64, D/64, B/2), 256 threads; kw/vw regs reused across 2 batches.
// ---------------------------------------------------------------------------
__global__ __launch_bounds__(256) void prep(const float* __restrict__ in,
                                            const float* __restrict__ kw,
                                            const float* __restrict__ vw,
                                            unsigned short* __restrict__ Kh,
                                            unsigned short* __restrict__ Vt) {
  const int lt = blockIdx.x * 64;
  const int dt = blockIdx.y * 64;
  const int t  = threadIdx.x;
  __shared__ unsigned short vtile[64][66];

  float4 kwv[4], vwv[4];
  #pragma unroll
  for (int i = 0; i < 4; ++i) {
    int c = i * 256 + t, r = c >> 4, c4 = (c & 15) * 4;
    size_t wi = (size_t)(lt + r) * D_ + dt + c4;
    kwv[i] = *(const float4*)(kw + wi);
    vwv[i] = *(const float4*)(vw + wi);
  }

  for (int bb = 0; bb < 2; ++bb) {
    const int b = blockIdx.z * 2 + bb;
    #pragma unroll
    for (int i = 0; i < 4; ++i) {
      int c = i * 256 + t, r = c >> 4, c4 = (c & 15) * 4;
      int j = lt + r;
      size_t gi = ((size_t)b * L_ + j) * D_ + dt + c4;
      float4 iv = *(const float4*)(in + gi);
      unsigned int p0 = f2h_bits(iv.x * kwv[i].x) | (f2h_bits(iv.y * kwv[i].y) << 16);
      unsigned int p1 = f2h_bits(iv.z * kwv[i].z) | (f2h_bits(iv.w * kwv[i].w) << 16);
      int gs = (((dt + c4) >> 3) ^ (j & 7));
      uint2 pk; pk.x = p0; pk.y = p1;
      *(uint2*)(Kh + ((size_t)b * L_ + j) * D_ + gs * 8 + (c4 & 7)) = pk;
      vtile[r][c4 + 0] = (unsigned short)f2h_bits(iv.x * vwv[i].x);
      vtile[r][c4 + 1] = (unsigned short)f2h_bits(iv.y * vwv[i].y);
      vtile[r][c4 + 2] = (unsigned short)f2h_bits(iv.z * vwv[i].z);
      vtile[r][c4 + 3] = (unsigned short)f2h_bits(iv.w * vwv[i].w);
    }
    __syncthreads();
    #pragma unroll
    for (int i = 0; i < 2; ++i) {
      int c = i * 256 + t, dd = c >> 3, l8 = (c & 7) * 8;
      int dg = dt + dd;
      int jglob = lt + l8;
      int ov[4];
      #pragma unroll
      for (int k2 = 0; k2 < 4; ++k2)
        ov[k2] = (int)((unsigned int)vtile[l8 + 2 * k2][dd] |
                       ((unsigned int)vtile[l8 + 2 * k2 + 1][dd] << 16));
      int gv  = (jglob & 31) >> 3;
      int key = (dg ^ (dg >> 2)) & 3;
      size_t idx = (((size_t)b * D_ + dg) * (L_ / BJ) + (jglob >> 5)) * BJ +
                   (size_t)((gv ^ key) * 8);
      intx4 o; o[0] = ov[0]; o[1] = ov[1]; o[2] = ov[2]; o[3] = ov[3];
      *(intx4*)(Vt + idx) = o;
    }
    __syncthreads();
  }
}

// ---------------------------------------------------------------------------
// flash: grid (L/BI, JSPLIT*B), 256 thr = 4 waves, 2 blocks/CU (69.5 KB LDS).
// QK: wave owns 16-row i-strip, Q in regs (A free), K frags from LDS.
// PV: re-partitioned — wave owns ALL 64 i-rows x 128-wide d-slice, so the V
//     tile is read ONCE per block (not 4x). P + al + l shared via LDS.
// 3 barriers/iter; K-DMA issued after B2 (hidden under PV), V-DMA after B3.
// ---------------------------------------------------------------------------
static __device__ __forceinline__ void stage_K(const unsigned short* Kg,
                                               unsigned short* Kl, int tid) {
  const int wb = tid & 192;
  #pragma unroll
  for (int i = 0; i < 8; ++i) {
    int gl = i * 256 + tid;
    async_ld16(Kg + (size_t)gl * 8, Kl + (i * 256 + wb) * 8);
  }
}
static __device__ __forceinline__ void stage_V(const unsigned short* Vg,
                                               unsigned short* Vl, int tid) {
  const int wb = tid & 192;
  #pragma unroll
  for (int i = 0; i < 8; ++i) {
    int gl = i * 256 + tid;
    int d = gl >> 2, g8 = gl & 3;
    async_ld16(Vg + (size_t)d * L_ + g8 * 8, Vl + (i * 256 + wb) * 8);
  }
}

__global__ __launch_bounds__(256, 2) void flash(const float* __restrict__ in,
                                                const float* __restrict__ qw,
                                                const unsigned short* __restrict__ Kh,
                                                const unsigned short* __restrict__ Vt,
                                                _Float16* __restrict__ Oh,
                                                float2* __restrict__ ml) {
  const int b    = blockIdx.y >> 1;
  const int g    = blockIdx.y & 1;       // j-half
  const int i0   = blockIdx.x * BI;
  const int tid  = threadIdx.x;
  const int w    = tid >> 6;
  const int lane = tid & 63;
  const int ln16 = lane & 15;
  const int quad = lane >> 4;

  __shared__ unsigned short Ksh[KTILE];          // 32 KB
  __shared__ unsigned short Vsh[VTILE];          // 32 KB
  __shared__ unsigned short Psh[BI * PSTRIDE];   //  5 KB
  __shared__ float alsh[BI];
  __shared__ float lsh[BI];

  const float kScale = 0.51012599f;  // log2(e)/sqrt(8): exp2-domain softmax

  // ---- Q fragments in registers (A-layout: m=ln16, k=quad*8+t) ----
  halfx8 qf[16];
  {
    const int qi = i0 + w * 16 + ln16;
    const float* ip = in + ((size_t)b * L_ + qi) * D_;
    const float* wp = qw + (size_t)qi * D_;
    #pragma unroll
    for (int ks = 0; ks < 16; ++ks) {
      int d0 = ks * 32 + quad * 8;
      float4 a0 = *(const float4*)(ip + d0);
      float4 a1 = *(const float4*)(ip + d0 + 4);
      float4 w0 = *(const float4*)(wp + d0);
      float4 w1 = *(const float4*)(wp + d0 + 4);
      halfx8 q;
      q[0] = (_Float16)(a0.x * w0.x * kScale);
      q[1] = (_Float16)(a0.y * w0.y * kScale);
      q[2] = (_Float16)(a0.z * w0.z * kScale);
      q[3] = (_Float16)(a0.w * w0.w * kScale);
      q[4] = (_Float16)(a1.x * w1.x * kScale);
      q[5] = (_Float16)(a1.y * w1.y * kScale);
      q[6] = (_Float16)(a1.z * w1.z * kScale);
      q[7] = (_Float16)(a1.w * w1.w * kScale);
      qf[ks] = q;
    }
  }

  float m_r[4], l_r[4];
  #pragma unroll
  for (int r = 0; r < 4; ++r) { m_r[r] = -1e30f; l_r[r] = 0.f; }
  floatx4 O[4][8];   // [mt][nt]: rows mt*16+quad*4+r, cols w*128+nt*16+ln16
  #pragma unroll
  for (int mt = 0; mt < 4; ++mt)
    #pragma unroll
    for (int nt = 0; nt < 8; ++nt) O[mt][nt] = (floatx4){0.f, 0.f, 0.f, 0.f};

  const unsigned short* KgB = Kh + ((size_t)b * L_ + g * JHALF) * D_;
  const unsigned short* VgB = Vt + (size_t)b * D_ * L_ + (size_t)g * JHALF;
  const int xk = ln16 & 7;
  const int xv = (ln16 ^ (ln16 >> 2)) & 3;

  // prologue: stage tile 0
  stage_K(KgB, Ksh, tid);
  stage_V(VgB, Vsh, tid);

  for (int jb = 0; jb < JITERS; ++jb) {
    __syncthreads();  // B1: DMA drained, K/V/P safe to read

    // ---- S = Q K^T (wave's 16 i x 32 j), 4 independent MFMA chains ----
    floatx4 acc[2][2];
    #pragma unroll
    for (int jt = 0; jt < 2; ++jt) {
      acc[jt][0] = (floatx4){0.f, 0.f, 0.f, 0.f};
      acc[jt][1] = (floatx4){0.f, 0.f, 0.f, 0.f};
      const unsigned short* kr = Ksh + (size_t)(jt * 16 + ln16) * D_;
      #pragma unroll
      for (int ks = 0; ks < 16; ++ks) {
        halfx8 bk = *(const halfx8*)(kr + (((4 * ks + quad) ^ xk) * 8));
        acc[jt][ks & 1] =
            __builtin_amdgcn_mfma_f32_16x16x32_f16(qf[ks], bk, acc[jt][ks & 1], 0, 0, 0);
      }
    }
    floatx4 sA[2];
    sA[0] = acc[0][0] + acc[0][1];
    sA[1] = acc[1][0] + acc[1][1];

    // ---- online softmax for own strip (DPP butterfly on VALU) ----
    float mx[4], al[4];
    #pragma unroll
    for (int r = 0; r < 4; ++r) mx[r] = dpp_bfly_max(fmaxf(sA[0][r], sA[1][r]));
    #pragma unroll
    for (int r = 0; r < 4; ++r) {
      float mn = fmaxf(m_r[r], mx[r]);
      al[r] = exp2f(m_r[r] - mn);
      m_r[r] = mn;
      float e0 = exp2f(sA[0][r] - mn);
      float e1 = exp2f(sA[1][r] - mn);
      sA[0][r] = e0; sA[1][r] = e1;
      l_r[r] = l_r[r] * al[r] + dpp_bfly_sum(e0 + e1);
    }

    // ---- publish P (f16) and al to LDS ----
    #pragma unroll
    for (int jt = 0; jt < 2; ++jt) {
      #pragma unroll
      for (int r = 0; r < 4; ++r)
        Psh[(w * 16 + quad * 4 + r) * PSTRIDE + jt * 16 + ln16] =
            (unsigned short)f2h_bits(sA[jt][r]);
    }
    if (ln16 == 0) {
      #pragma unroll
      for (int r = 0; r < 4; ++r) alsh[w * 16 + quad * 4 + r] = al[r];
    }
    __syncthreads();  // B2: P + al visible; K phase complete

    if (jb + 1 < JITERS)
      stage_K(KgB + (size_t)(jb + 1) * KTILE, Ksh, tid);  // hides under PV

    // ---- PV (block-cooperative): wave owns all 64 i x d-slice [w*128, +128) ----
    halfx8 pf[4];
    #pragma unroll
    for (int mt = 0; mt < 4; ++mt)
      pf[mt] = *(const halfx8*)(&Psh[(mt * 16 + ln16) * PSTRIDE + quad * 8]);

    #pragma unroll
    for (int mt = 0; mt < 4; ++mt) {
      float a0 = alsh[mt * 16 + quad * 4 + 0];
      float a1 = alsh[mt * 16 + quad * 4 + 1];
      float a2 = alsh[mt * 16 + quad * 4 + 2];
      float a3 = alsh[mt * 16 + quad * 4 + 3];
      #pragma unroll
      for (int nt = 0; nt < 8; ++nt) {
        O[mt][nt][0] *= a0; O[mt][nt][1] *= a1;
        O[mt][nt][2] *= a2; O[mt][nt][3] *= a3;
      }
    }

    const unsigned short* vb0 =
        Vsh + (size_t)(w * 128 + ln16) * BJ + ((quad ^ xv) * 8);
    #pragma unroll
    for (int nt = 0; nt < 8; ++nt) {
      halfx8 vf = *(const halfx8*)(vb0 + (size_t)nt * 16 * BJ);
      #pragma unroll
      for (int mt = 0; mt < 4; ++mt)
        O[mt][nt] = __builtin_amdgcn_mfma_f32_16x16x32_f16(pf[mt], vf, O[mt][nt], 0, 0, 0);
    }
    __syncthreads();  // B3: PV complete (Vsh/Psh free)

    if (jb + 1 < JITERS)
      stage_V(VgB + (jb + 1) * BJ, Vsh, tid);
  }

  // ---- epilogue: publish l, write partial Oh (f16) + ml ----
  if (ln16 == 0) {
    #pragma unroll
    for (int r = 0; r < 4; ++r) lsh[w * 16 + quad * 4 + r] = l_r[r];
  }
  __syncthreads();

  const size_t rowbase = (size_t)g * NROWS + (size_t)b * L_ + i0;
  #pragma unroll
  for (int mt = 0; mt < 4; ++mt) {
    #pragma unroll
    for (int r = 0; r < 4; ++r) {
      float linv = 1.0f / lsh[mt * 16 + quad * 4 + r];
      _Float16* op = Oh + (rowbase + mt * 16 + quad * 4 + r) * D_ + w * 128 + ln16;
      #pragma unroll
      for (int nt = 0; nt < 8; ++nt)
        op[nt * 16] = (_Float16)(O[mt][nt][r] * linv);
    }
  }
  if (ln16 == 0) {
    #pragma unroll
    for (int r = 0; r < 4; ++r) {
      float2 v; v.x = m_r[r]; v.y = l_r[r];
      ml[rowbase + w * 16 + quad * 4 + r] = v;
    }
  }
}

// ---------------------------------------------------------------------------
// combine: out = (a1*O1 + a2*O2)/(a1+a2), a_g = exp2(m_g - M) * l_g
// ---------------------------------------------------------------------------
__global__ __launch_bounds__(256) void combine(const _Float16* __restrict__ Oh,
                                               const float2* __restrict__ ml,
                                               float* __restrict__ out) {
  const int row = blockIdx.x * 4 + (threadIdx.x >> 6);
  const int d0  = (threadIdx.x & 63) * 8;
  float2 m1 = ml[row];
  float2 m2 = ml[NROWS + row];
  float M  = fmaxf(m1.x, m2.x);
  float a1 = exp2f(m1.x - M) * m1.y;
  float a2 = exp2f(m2.x - M) * m2.y;
  float inv = 1.0f / (a1 + a2);
  float w1 = a1 * inv, w2 = a2 * inv;
  halfx8 o1 = *(const halfx8*)(Oh + (size_t)row * D_ + d0);
  halfx8 o2 = *(const halfx8*)(Oh + ((size_t)NROWS + row) * D_ + d0);
  float4 r0, r1;
  r0.x = w1 * (float)o1[0] + w2 * (float)o2[0];
  r0.y = w1 * (float)o1[1] + w2 * (float)o2[1];
  r0.z = w1 * (float)o1[2] + w2 * (float)o2[2];
  r0.w = w1 * (float)o1[3] + w2 * (float)o2[3];
  r1.x = w1 * (float)o1[4] + w2 * (float)o2[4];
  r1.y = w1 * (float)o1[5] + w2 * (float)o2[5];
  r1.z = w1 * (float)o1[6] + w2 * (float)o2[6];
  r1.w = w1 * (float)o1[7] + w2 * (float)o2[7];
  *(float4*)(out + (size_t)row * D_ + d0)     = r0;
  *(float4*)(out + (size_t)row * D_ + d0 + 4) = r1;
}

// ---------------------------------------------------------------------------
extern "C" void kernel_launch(void* const* d_in, const int* in_sizes, int n_in,
                              void* d_out, int out_size, void* d_ws, size_t ws_size,
                              hipStream_t stream) {
  const float* in = (const float*)d_in[0];
  const float* qw = (const float*)d_in[1];
  const float* kw = (const float*)d_in[2];
  const float* vw = (const float*)d_in[3];
  float* out = (float*)d_out;

  unsigned short* Kh = (unsigned short*)d_ws;                 // 16.78 MB
  unsigned short* Vt = Kh + (size_t)B_ * L_ * D_;             // 16.78 MB
  _Float16* Oh = (_Float16*)(Vt + (size_t)B_ * L_ * D_);      // 33.55 MB
  float2* ml = (float2*)(Oh + (size_t)JSPLIT * NROWS * D_);   //  0.26 MB

  prep<<<dim3(L_ / 64, D_ / 64, B_ / 2), dim3(256), 0, stream>>>(in, kw, vw, Kh, Vt);
  flash<<<dim3(L_ / BI, JSPLIT * B_), dim3(256), 0, stream>>>(in, qw, Kh, Vt, Oh, ml);
  combine<<<dim3(NROWS / 4), dim3(256), 0, stream>>>(Oh, ml, out);
}

// Round 6
// 282.626 us; speedup vs baseline: 1.5097x; 1.3477x over previous
//
#include <hip/hip_runtime.h>

#define B_ 8
#define L_ 2048
#define D_ 512
#define BI 64
#define BJ 64
#define JITERS (L_ / BJ)           // 32
#define PSTRIDE 72                 // 64 + 8 f16; rows 144 B (16B-aligned)

typedef __attribute__((ext_vector_type(4))) float  floatx4;
typedef __attribute__((ext_vector_type(8))) _Float16 halfx8;
typedef __attribute__((ext_vector_type(4))) int    intx4;

static __device__ __forceinline__ unsigned int f2h_bits(float x) {
  _Float16 h = (_Float16)x;
  return (unsigned int)__builtin_bit_cast(unsigned short, h);
}

static __device__ __forceinline__ void async_ld16(const unsigned short* g,
                                                  unsigned short* l) {
  __builtin_amdgcn_global_load_lds(
      (const __attribute__((address_space(1))) unsigned int*)g,
      (__attribute__((address_space(3))) unsigned int*)l, 16, 0, 0);
}

// 16-lane butterfly reductions on the VALU (DPP) — off the LDS pipe.
static __device__ __forceinline__ float dpp_bfly_max(float x) {
  int v; float y;
  v = __builtin_bit_cast(int, x);
  y = __builtin_bit_cast(float, __builtin_amdgcn_update_dpp(v, v, 0xB1, 0xF, 0xF, true));
  x = fmaxf(x, y);
  v = __builtin_bit_cast(int, x);
  y = __builtin_bit_cast(float, __builtin_amdgcn_update_dpp(v, v, 0x4E, 0xF, 0xF, true));
  x = fmaxf(x, y);
  v = __builtin_bit_cast(int, x);
  y = __builtin_bit_cast(float, __builtin_amdgcn_update_dpp(v, v, 0x141, 0xF, 0xF, true));
  x = fmaxf(x, y);
  v = __builtin_bit_cast(int, x);
  y = __builtin_bit_cast(float, __builtin_amdgcn_update_dpp(v, v, 0x140, 0xF, 0xF, true));
  x = fmaxf(x, y);
  return x;
}

static __device__ __forceinline__ float dpp_bfly_sum(float x) {
  int v; float y;
  v = __builtin_bit_cast(int, x);
  y = __builtin_bit_cast(float, __builtin_amdgcn_update_dpp(v, v, 0xB1, 0xF, 0xF, true));
  x += y;
  v = __builtin_bit_cast(int, x);
  y = __builtin_bit_cast(float, __builtin_amdgcn_update_dpp(v, v, 0x4E, 0xF, 0xF, true));
  x += y;
  v = __builtin_bit_cast(int, x);
  y = __builtin_bit_cast(float, __builtin_amdgcn_update_dpp(v, v, 0x141, 0xF, 0xF, true));
  x += y;
  v = __builtin_bit_cast(int, x);
  y = __builtin_bit_cast(float, __builtin_amdgcn_update_dpp(v, v, 0x140, 0xF, 0xF, true));
  x += y;
  return x;
}

// ---------------------------------------------------------------------------
// prep (R1-proven): Kh[b][l][d] = in*kw (LINEAR); Vt[b][d][l] = in*vw (LINEAR,
// transposed via LDS). All swizzling now lives in flash's DMA source addresses.
// grid: (L/64, D/64, B), 256 threads
// ---------------------------------------------------------------------------
__global__ __launch_bounds__(256) void prep_kv(const float* __restrict__ in,
                                               const float* __restrict__ kw,
                                               const float* __restrict__ vw,
                                               unsigned short* __restrict__ Kh,
                                               unsigned short* __restrict__ Vt) {
  const int lt = blockIdx.x * 64;
  const int dt = blockIdx.y * 64;
  const int b  = blockIdx.z;
  const int t  = threadIdx.x;
  __shared__ unsigned short vtile[64][66];

  #pragma unroll
  for (int i = 0; i < 4; ++i) {
    int c  = i * 256 + t;
    int r  = c >> 4;
    int c4 = (c & 15) * 4;
    size_t gi = ((size_t)b * L_ + (lt + r)) * D_ + (dt + c4);
    size_t wi = (size_t)(lt + r) * D_ + (dt + c4);
    float4 iv = *(const float4*)(in + gi);
    float4 kv = *(const float4*)(kw + wi);
    float4 vv = *(const float4*)(vw + wi);
    unsigned int p0 = f2h_bits(iv.x * kv.x) | (f2h_bits(iv.y * kv.y) << 16);
    unsigned int p1 = f2h_bits(iv.z * kv.z) | (f2h_bits(iv.w * kv.w) << 16);
    uint2 pk; pk.x = p0; pk.y = p1;
    *(uint2*)(Kh + gi) = pk;
    vtile[r][c4 + 0] = (unsigned short)f2h_bits(iv.x * vv.x);
    vtile[r][c4 + 1] = (unsigned short)f2h_bits(iv.y * vv.y);
    vtile[r][c4 + 2] = (unsigned short)f2h_bits(iv.z * vv.z);
    vtile[r][c4 + 3] = (unsigned short)f2h_bits(iv.w * vv.w);
  }
  __syncthreads();
  #pragma unroll
  for (int i = 0; i < 2; ++i) {
    int c  = i * 256 + t;
    int dd = c >> 3;
    int l8 = (c & 7) * 8;
    int ov[4];
    #pragma unroll
    for (int j = 0; j < 4; ++j) {
      ov[j] = (int)((unsigned int)vtile[l8 + 2 * j][dd] |
                    ((unsigned int)vtile[l8 + 2 * j + 1][dd] << 16));
    }
    intx4 o; o[0] = ov[0]; o[1] = ov[1]; o[2] = ov[2]; o[3] = ov[3];
    *(intx4*)(Vt + ((size_t)b * D_ + (dt + dd)) * L_ + (lt + l8)) = o;
  }
}

// ---------------------------------------------------------------------------
// flash (refined R1): grid (L/BI, B), 256 thr = 4 waves, 1 block/CU (137 KB).
// Split-phase async staging: K-DMA(jb+1) after Bmid (drains at Bend, hidden
// under PV); V-DMA(jb+1) after Bend (drains at next Bmid, hidden under QK).
// DMA source carries the bank-swizzle (slot = g ^ (row&7)); LDS stays linear.
// ---------------------------------------------------------------------------
static __device__ __forceinline__ void stage_K(const unsigned short* Kg,
                                               unsigned short* Kl, int tid) {
  const int wb = tid & 192;  // wave-uniform LDS base component
  #pragma unroll
  for (int i = 0; i < 16; ++i) {
    int sIdx = i * 256 + tid;          // 0..4095 16B-slots of the 64KB tile
    int j = sIdx >> 6, sl = sIdx & 63; // row j (64 rows x 64 slots)
    async_ld16(Kg + (size_t)j * D_ + ((sl ^ (j & 7)) * 8),
               Kl + (size_t)(i * 256 + wb) * 8);
  }
}
static __device__ __forceinline__ void stage_V(const unsigned short* Vg,
                                               unsigned short* Vl, int tid) {
  const int wb = tid & 192;
  #pragma unroll
  for (int i = 0; i < 16; ++i) {
    int sIdx = i * 256 + tid;          // 0..4095 slots (512 rows x 8 slots)
    int d = sIdx >> 3, sl = sIdx & 7;
    async_ld16(Vg + (size_t)d * L_ + ((sl ^ (d & 7)) * 8),
               Vl + (size_t)(i * 256 + wb) * 8);
  }
}

__global__ __launch_bounds__(256, 1) void flash(const float* __restrict__ in,
                                                const float* __restrict__ qw,
                                                const unsigned short* __restrict__ Kh,
                                                const unsigned short* __restrict__ Vt,
                                                float* __restrict__ out) {
  const int b    = blockIdx.y;
  const int i0   = blockIdx.x * BI;
  const int tid  = threadIdx.x;
  const int w    = tid >> 6;
  const int lane = tid & 63;
  const int ln16 = lane & 15;
  const int quad = lane >> 4;

  __shared__ unsigned short Ksh[BJ * D_];        // 64 KB, row = j, 64 slots
  __shared__ unsigned short Vsh[D_ * BJ];        // 64 KB, row = d, 8 slots
  __shared__ unsigned short Psh[BI * PSTRIDE];   //  9 KB

  const float kScale = 0.51012599f;  // log2(e)/sqrt(8): exp2-domain softmax

  // ---- Q fragments in registers (A-layout: m=ln16, k=quad*8+t) ----
  halfx8 qf[16];
  {
    const int qi = i0 + w * 16 + ln16;
    const float* ip = in + ((size_t)b * L_ + qi) * D_;
    const float* wp = qw + (size_t)qi * D_;
    #pragma unroll
    for (int ks = 0; ks < 16; ++ks) {
      int d0 = ks * 32 + quad * 8;
      float4 a0 = *(const float4*)(ip + d0);
      float4 a1 = *(const float4*)(ip + d0 + 4);
      float4 w0 = *(const float4*)(wp + d0);
      float4 w1 = *(const float4*)(wp + d0 + 4);
      halfx8 q;
      q[0] = (_Float16)(a0.x * w0.x * kScale);
      q[1] = (_Float16)(a0.y * w0.y * kScale);
      q[2] = (_Float16)(a0.z * w0.z * kScale);
      q[3] = (_Float16)(a0.w * w0.w * kScale);
      q[4] = (_Float16)(a1.x * w1.x * kScale);
      q[5] = (_Float16)(a1.y * w1.y * kScale);
      q[6] = (_Float16)(a1.z * w1.z * kScale);
      q[7] = (_Float16)(a1.w * w1.w * kScale);
      qf[ks] = q;
    }
  }

  float m_r[4], l_r[4];
  #pragma unroll
  for (int r = 0; r < 4; ++r) { m_r[r] = -1e30f; l_r[r] = 0.f; }
  floatx4 O[32];
  #pragma unroll
  for (int ct = 0; ct < 32; ++ct) O[ct] = (floatx4){0.f, 0.f, 0.f, 0.f};

  const unsigned short* KgB = Kh + (size_t)b * L_ * D_;
  const unsigned short* VgB = Vt + (size_t)b * D_ * L_;
  const int xk = ln16 & 7;

  // prologue: stage tile 0 (single exposed drain)
  stage_K(KgB, Ksh, tid);
  stage_V(VgB, Vsh, tid);
  __syncthreads();

  for (int jb = 0; jb < JITERS; ++jb) {
    // ---- S = Q K^T (wave's 16 i x 64 j): 4 independent MFMA chains ----
    floatx4 sA[4];
    #pragma unroll
    for (int jt = 0; jt < 4; ++jt) {
      floatx4 acc = (floatx4){0.f, 0.f, 0.f, 0.f};
      const unsigned short* kr = Ksh + (size_t)(jt * 16 + ln16) * D_;
      #pragma unroll
      for (int ks = 0; ks < 16; ++ks) {
        halfx8 bk = *(const halfx8*)(kr + (((ks * 4 + quad) ^ xk) * 8));
        acc = __builtin_amdgcn_mfma_f32_16x16x32_f16(qf[ks], bk, acc, 0, 0, 0);
      }
      sA[jt] = acc;
    }

    // ---- online softmax (DPP butterfly on VALU) ----
    float mt[4], al[4];
    #pragma unroll
    for (int r = 0; r < 4; ++r)
      mt[r] = dpp_bfly_max(fmaxf(fmaxf(sA[0][r], sA[1][r]),
                                 fmaxf(sA[2][r], sA[3][r])));
    bool upd = false;
    #pragma unroll
    for (int r = 0; r < 4; ++r) {
      float mn = fmaxf(m_r[r], mt[r]);
      al[r] = exp2f(m_r[r] - mn);
      upd = upd || (mn != m_r[r]);
      m_r[r] = mn;
      float e0 = exp2f(sA[0][r] - mn);
      float e1 = exp2f(sA[1][r] - mn);
      float e2 = exp2f(sA[2][r] - mn);
      float e3 = exp2f(sA[3][r] - mn);
      sA[0][r] = e0; sA[1][r] = e1; sA[2][r] = e2; sA[3][r] = e3;
      l_r[r] = l_r[r] * al[r] + dpp_bfly_sum((e0 + e1) + (e2 + e3));
    }

    if (__any((int)upd)) {
      #pragma unroll
      for (int ct = 0; ct < 32; ++ct) {
        #pragma unroll
        for (int r = 0; r < 4; ++r) O[ct][r] *= al[r];
      }
    }

    // ---- P: C-layout -> A-layout via LDS (same wave, no barrier) ----
    #pragma unroll
    for (int jt = 0; jt < 4; ++jt) {
      #pragma unroll
      for (int r = 0; r < 4; ++r)
        Psh[(w * 16 + quad * 4 + r) * PSTRIDE + jt * 16 + ln16] =
            (unsigned short)f2h_bits(sA[jt][r]);
    }
    halfx8 pf[2];
    #pragma unroll
    for (int kc = 0; kc < 2; ++kc)
      pf[kc] = *(const halfx8*)(&Psh[(w * 16 + ln16) * PSTRIDE + kc * 32 + quad * 8]);

    __syncthreads();  // Bmid: all waves done with Ksh; drains V-DMA(jb) [covered by QK]
    if (jb + 1 < JITERS)
      stage_K(KgB + (size_t)(jb + 1) * BJ * D_, Ksh, tid);  // hides under PV

    // ---- O += P V (64 MFMA, 32 chains) ----
    #pragma unroll
    for (int ct = 0; ct < 32; ++ct) {
      const unsigned short* vr = Vsh + (size_t)(ct * 16 + ln16) * BJ;
      #pragma unroll
      for (int kc = 0; kc < 2; ++kc) {
        halfx8 vf = *(const halfx8*)(vr + (((kc * 4 + quad) ^ xk) * 8));
        O[ct] = __builtin_amdgcn_mfma_f32_16x16x32_f16(pf[kc], vf, O[ct], 0, 0, 0);
      }
    }

    __syncthreads();  // Bend: all waves done with Vsh; drains K-DMA(jb+1) [covered by PV]
    if (jb + 1 < JITERS)
      stage_V(VgB + (jb + 1) * BJ, Vsh, tid);  // hides under next QK
  }

  // ---- epilogue: out = O / l (direct f32, no combine pass) ----
  float inv[4];
  #pragma unroll
  for (int r = 0; r < 4; ++r) inv[r] = 1.0f / l_r[r];
  float* op = out + ((size_t)b * L_ + i0 + w * 16 + quad * 4) * D_ + ln16;
  #pragma unroll
  for (int r = 0; r < 4; ++r) {
    #pragma unroll
    for (int ct = 0; ct < 32; ++ct)
      op[(size_t)r * D_ + ct * 16] = O[ct][r] * inv[r];
  }
}

// ---------------------------------------------------------------------------
extern "C" void kernel_launch(void* const* d_in, const int* in_sizes, int n_in,
                              void* d_out, int out_size, void* d_ws, size_t ws_size,
                              hipStream_t stream) {
  const float* in = (const float*)d_in[0];
  const float* qw = (const float*)d_in[1];
  const float* kw = (const float*)d_in[2];
  const float* vw = (const float*)d_in[3];
  float* out = (float*)d_out;

  unsigned short* Kh = (unsigned short*)d_ws;                 // 16.78 MB
  unsigned short* Vt = Kh + (size_t)B_ * L_ * D_;             // 16.78 MB

  prep_kv<<<dim3(L_ / 64, D_ / 64, B_), dim3(256), 0, stream>>>(in, kw, vw, Kh, Vt);
  flash<<<dim3(L_ / BI, B_), dim3(256), 0, stream>>>(in, qw, Kh, Vt, out);
}